// Round 3
// 568.832 us; speedup vs baseline: 1.0654x; 1.0654x over previous
//
#include <hip/hip_runtime.h>
#include <cstdint>
#include <cstddef>

// Problem constants
#define Bn 16
#define Tn 128
#define Dn 8192    // C*H*W
#define Fn 16      // NUM_FEAT
#define Gn 4096    // NUM_FEAT*H*W
#define MT (Bn*Tn) // 2048 rows

typedef __attribute__((ext_vector_type(8))) short short8;
typedef __attribute__((ext_vector_type(4))) float f32x4;

__device__ inline short f2bf(float f) {
    union { float f; uint32_t u; } c; c.f = f;
    uint32_t u = c.u;
    uint32_t r = (u + 0x7FFFu + ((u >> 16) & 1u)) >> 16;
    return (short)(r & 0xFFFFu);
}

__device__ inline short8 cvt8(float4 a, float4 b) {
    short8 v;
    v[0] = f2bf(a.x); v[1] = f2bf(a.y); v[2] = f2bf(a.z); v[3] = f2bf(a.w);
    v[4] = f2bf(b.x); v[5] = f2bf(b.y); v[6] = f2bf(b.z); v[7] = f2bf(b.w);
    return v;
}

// ---------------------------------------------------------------------------
// Fused fp32->bf16 convert for x1 and w3 (one launch, grid-stride).
// ---------------------------------------------------------------------------
#define N8_X1 (MT * Dn / 8)   // 2,097,152
#define N8_W3 ((size_t)Gn * Dn / 8)   // 4,194,304

__global__ __launch_bounds__(256) void cvt2_kernel(
    const float* __restrict__ x1, const float* __restrict__ w3,
    short* __restrict__ x1b, short* __restrict__ w3b)
{
    const size_t total = N8_X1 + N8_W3;
    size_t i = (size_t)blockIdx.x * 256 + threadIdx.x;
    const size_t stride = (size_t)gridDim.x * 256;
    for (; i < total; i += stride) {
        if (i < N8_X1) {
            const float4* s = ((const float4*)x1) + i * 2;
            ((short8*)x1b)[i] = cvt8(s[0], s[1]);
        } else {
            const size_t j = i - N8_X1;
            const float4* s = ((const float4*)w3) + j * 2;
            ((short8*)w3b)[j] = cvt8(s[0], s[1]);
        }
    }
}

// ---------------------------------------------------------------------------
// qk skinny GEMM: q = x1b @ w1^T + b1 (bf16 A), k = x2 @ w2^T + b2 (inline cvt).
// Grid 256 blocks x 256 threads. Block = (16-row m-tile, q-or-k).
// ---------------------------------------------------------------------------
__global__ __launch_bounds__(256) void qk_gemm_kernel(
    const short* __restrict__ x1b, const float* __restrict__ x2,
    const float* __restrict__ w1, const float* __restrict__ w2,
    const float* __restrict__ b1, const float* __restrict__ b2,
    float* __restrict__ q, float* __restrict__ k)
{
    __shared__ float red[4][16][16];
    const int tid = threadIdx.x;
    const int tile = blockIdx.x >> 1;
    const int isK  = blockIdx.x & 1;
    const int m0 = tile * 16;
    const int wave = tid >> 6, lane = tid & 63;
    const int quad = lane >> 4, r = lane & 15;
    const int kbase = wave * (Dn / 4);   // 2048

    f32x4 acc = {};

    if (!isK) {
        const short* ap = x1b + (size_t)(m0 + r) * Dn + kbase + quad * 8;
        const float* bp = w1 + (size_t)r * Dn + kbase + quad * 8;
        #pragma unroll 4
        for (int it = 0; it < 64; ++it) {
            short8 af = *(const short8*)(ap + it * 32);
            const float4* b4 = (const float4*)(bp + it * 32);
            short8 bf = cvt8(b4[0], b4[1]);
            acc = __builtin_amdgcn_mfma_f32_16x16x32_bf16(af, bf, acc, 0, 0, 0);
        }
    } else {
        const float* apf = x2 + (size_t)(m0 + r) * Dn + kbase + quad * 8;
        const float* bp  = w2 + (size_t)r * Dn + kbase + quad * 8;
        #pragma unroll 4
        for (int it = 0; it < 64; ++it) {
            const float4* a4 = (const float4*)(apf + it * 32);
            short8 af = cvt8(a4[0], a4[1]);
            const float4* b4 = (const float4*)(bp + it * 32);
            short8 bf = cvt8(b4[0], b4[1]);
            acc = __builtin_amdgcn_mfma_f32_16x16x32_bf16(af, bf, acc, 0, 0, 0);
        }
    }

    // C/D: col(n=f)=lane&15, row(m)=quad*4+reg
    #pragma unroll
    for (int reg = 0; reg < 4; ++reg)
        red[wave][quad * 4 + reg][r] = acc[reg];
    __syncthreads();

    const int m = tid >> 4, f = tid & 15;
    float s = red[0][m][f] + red[1][m][f] + red[2][m][f] + red[3][m][f];
    s += (isK ? b2 : b1)[f];
    (isK ? k : q)[(m0 + m) * Fn + f] = s;
}

// ---------------------------------------------------------------------------
// attn: scores = q @ k^T per batch; softmax over t (axis=1!). Output bf16.
// ---------------------------------------------------------------------------
__global__ __launch_bounds__(128) void attn_kernel(
    const float* __restrict__ q, const float* __restrict__ k,
    short* __restrict__ attn16)
{
    __shared__ float qs[Tn * 17];
    const int b = blockIdx.x;
    const int tid = threadIdx.x;   // = s

    for (int i = tid; i < Tn * Fn; i += 128)
        qs[(i >> 4) * 17 + (i & 15)] = q[b * Tn * Fn + i];
    __syncthreads();

    float kr[16];
    #pragma unroll
    for (int f = 0; f < 16; ++f) kr[f] = k[b * Tn * Fn + tid * Fn + f];

    float m = -1e30f, sum = 0.f;
    #pragma unroll 1
    for (int t = 0; t < Tn; ++t) {
        float sc = 0.f;
        #pragma unroll
        for (int f = 0; f < 16; ++f) sc += qs[t * 17 + f] * kr[f];
        if (sc > m) { sum = sum * __expf(m - sc) + 1.f; m = sc; }
        else        { sum += __expf(sc - m); }
    }
    const float inv = 1.f / sum;
    short* ap = attn16 + (size_t)b * Tn * Tn;
    #pragma unroll 1
    for (int t = 0; t < Tn; ++t) {
        float sc = 0.f;
        #pragma unroll
        for (int f = 0; f < 16; ++f) sc += qs[t * 17 + f] * kr[f];
        ap[t * Tn + tid] = f2bf(__expf(sc - m) * inv);
    }
}

// ---------------------------------------------------------------------------
// Big GEMM, split-K by 2, DETERMINISTIC: each K-half z writes its own fp32
// partial buffer vTf[z] (plain stores — no atomics, no memset, no host API).
// Grid (16, 32, 2) = 1024 blocks -> 4 blocks/CU (vs 2): occupancy 21%->~42%.
// m97 structure, BK=32, 128x128 tile per block.
// ---------------------------------------------------------------------------
#define BK 32
#define KSPLIT 2
#define KHALF (Dn / KSPLIT)   // 4096

__global__ __launch_bounds__(256) void gemm_v_split_kernel(
    const short* __restrict__ A, const short* __restrict__ Bw,
    float* __restrict__ vTf)
{
    __shared__ __attribute__((aligned(16))) short As[128 * BK];
    __shared__ __attribute__((aligned(16))) short Bs[128 * BK];

    const int tid = threadIdx.x;
    const int m0 = blockIdx.y * 128;        // g dim (4096)
    const int n0 = blockIdx.x * 128;        // bt dim (2048)
    const int z  = blockIdx.z;              // K half
    const int kbase = z * KHALF;
    float* outp = vTf + (size_t)z * Gn * MT;
    const int wave = tid >> 6, lane = tid & 63;
    const int wm = (wave >> 1) * 64, wn = (wave & 1) * 64;
    const int quad = lane >> 4, r = lane & 15;

    const int srow = wave * 32 + (lane >> 2);
    const int scol = (lane & 3) * 8;
    const short* gA = A  + (size_t)(m0 + srow) * Dn + kbase + scol;
    const short* gB = Bw + (size_t)(n0 + srow) * Dn + kbase + scol;
    short* lA = &As[srow * BK + scol];
    short* lB = &Bs[srow * BK + scol];

    f32x4 acc[4][4] = {};

    #pragma unroll 1
    for (int k0 = 0; k0 < KHALF; k0 += BK) {
        __syncthreads();
        __builtin_amdgcn_global_load_lds(
            (const __attribute__((address_space(1))) void*)(gA + k0),
            (__attribute__((address_space(3))) void*)lA, 16, 0, 0);
        __builtin_amdgcn_global_load_lds(
            (const __attribute__((address_space(1))) void*)(gA + k0 + (size_t)16 * Dn),
            (__attribute__((address_space(3))) void*)(lA + 16 * BK), 16, 0, 0);
        __builtin_amdgcn_global_load_lds(
            (const __attribute__((address_space(1))) void*)(gB + k0),
            (__attribute__((address_space(3))) void*)lB, 16, 0, 0);
        __builtin_amdgcn_global_load_lds(
            (const __attribute__((address_space(1))) void*)(gB + k0 + (size_t)16 * Dn),
            (__attribute__((address_space(3))) void*)(lB + 16 * BK), 16, 0, 0);
        __syncthreads();

        short8 af[4], bf[4];
        #pragma unroll
        for (int i = 0; i < 4; ++i)
            af[i] = *(const short8*)&As[(wm + i * 16 + r) * BK + quad * 8];
        #pragma unroll
        for (int j = 0; j < 4; ++j)
            bf[j] = *(const short8*)&Bs[(wn + j * 16 + r) * BK + quad * 8];

        #pragma unroll
        for (int i = 0; i < 4; ++i)
            #pragma unroll
            for (int j = 0; j < 4; ++j)
                acc[i][j] = __builtin_amdgcn_mfma_f32_16x16x32_bf16(
                    af[i], bf[j], acc[i][j], 0, 0, 0);
    }

    // C/D: col(n=bt)=lane&15 group, row(m=g)=quad*4+reg. Plain fp32 stores.
    #pragma unroll
    for (int i = 0; i < 4; ++i) {
        #pragma unroll
        for (int reg = 0; reg < 4; ++reg) {
            const int rowg = m0 + wm + i * 16 + quad * 4 + reg;
            #pragma unroll
            for (int j = 0; j < 4; ++j) {
                const int col = n0 + wn + j * 16 + r;
                outp[(size_t)rowg * MT + col] = acc[i][j][reg];
            }
        }
    }
}

// Sum the two K-half partials + bias, fp32->bf16. row g = i>>8 (MT/8=256/row).
__global__ __launch_bounds__(256) void vt_cvt_kernel(
    const float* __restrict__ vTf, const float* __restrict__ bias,
    short* __restrict__ vT)
{
    const size_t N8 = (size_t)Gn * MT / 8;   // 1,048,576
    const float4* p0 = (const float4*)vTf;
    const float4* p1 = (const float4*)(vTf + (size_t)Gn * MT);
    size_t i = (size_t)blockIdx.x * 256 + threadIdx.x;
    const size_t stride = (size_t)gridDim.x * 256;
    for (; i < N8; i += stride) {
        const float bv = bias[i >> 8];
        float4 a0 = p0[i * 2], b0 = p0[i * 2 + 1];
        float4 a1 = p1[i * 2], b1 = p1[i * 2 + 1];
        a0.x += a1.x + bv; a0.y += a1.y + bv; a0.z += a1.z + bv; a0.w += a1.w + bv;
        b0.x += b1.x + bv; b0.y += b1.y + bv; b0.z += b1.z + bv; b0.w += b1.w + bv;
        ((short8*)vT)[i] = cvt8(a0, b0);
    }
}

// ---------------------------------------------------------------------------
// Fallback (ws too small for split-K): original single-pass big GEMM.
// ---------------------------------------------------------------------------
__global__ __launch_bounds__(256) void gemm_v_kernel(
    const short* __restrict__ A, const short* __restrict__ Bw,
    const float* __restrict__ bias, short* __restrict__ vT)
{
    __shared__ __attribute__((aligned(16))) short As[128 * BK];
    __shared__ __attribute__((aligned(16))) short Bs[128 * BK];

    const int tid = threadIdx.x;
    const int m0 = blockIdx.y * 128;   // g dim (4096)
    const int n0 = blockIdx.x * 128;   // bt dim (2048)
    const int wave = tid >> 6, lane = tid & 63;
    const int wm = (wave >> 1) * 64, wn = (wave & 1) * 64;
    const int quad = lane >> 4, r = lane & 15;

    const int srow = wave * 32 + (lane >> 2);
    const int scol = (lane & 3) * 8;
    const short* gA = A  + (size_t)(m0 + srow) * Dn + scol;
    const short* gB = Bw + (size_t)(n0 + srow) * Dn + scol;
    short* lA = &As[srow * BK + scol];
    short* lB = &Bs[srow * BK + scol];

    f32x4 acc[4][4] = {};

    #pragma unroll 1
    for (int k0 = 0; k0 < Dn; k0 += BK) {
        __syncthreads();
        __builtin_amdgcn_global_load_lds(
            (const __attribute__((address_space(1))) void*)(gA + k0),
            (__attribute__((address_space(3))) void*)lA, 16, 0, 0);
        __builtin_amdgcn_global_load_lds(
            (const __attribute__((address_space(1))) void*)(gA + k0 + (size_t)16 * Dn),
            (__attribute__((address_space(3))) void*)(lA + 16 * BK), 16, 0, 0);
        __builtin_amdgcn_global_load_lds(
            (const __attribute__((address_space(1))) void*)(gB + k0),
            (__attribute__((address_space(3))) void*)lB, 16, 0, 0);
        __builtin_amdgcn_global_load_lds(
            (const __attribute__((address_space(1))) void*)(gB + k0 + (size_t)16 * Dn),
            (__attribute__((address_space(3))) void*)(lB + 16 * BK), 16, 0, 0);
        __syncthreads();

        short8 af[4], bf[4];
        #pragma unroll
        for (int i = 0; i < 4; ++i)
            af[i] = *(const short8*)&As[(wm + i * 16 + r) * BK + quad * 8];
        #pragma unroll
        for (int j = 0; j < 4; ++j)
            bf[j] = *(const short8*)&Bs[(wn + j * 16 + r) * BK + quad * 8];

        #pragma unroll
        for (int i = 0; i < 4; ++i)
            #pragma unroll
            for (int j = 0; j < 4; ++j)
                acc[i][j] = __builtin_amdgcn_mfma_f32_16x16x32_bf16(
                    af[i], bf[j], acc[i][j], 0, 0, 0);
    }

    #pragma unroll
    for (int i = 0; i < 4; ++i) {
        #pragma unroll
        for (int reg = 0; reg < 4; ++reg) {
            const int rowg = m0 + wm + i * 16 + quad * 4 + reg;
            const float bv = bias[rowg];
            #pragma unroll
            for (int j = 0; j < 4; ++j) {
                const int col = n0 + wn + j * 16 + r;
                vT[(size_t)rowg * MT + col] = f2bf(acc[i][j][reg] + bv);
            }
        }
    }
}

// ---------------------------------------------------------------------------
// out GEMM per batch: out[t][g] = sum_s attn[t][s] * vT[g][s].
// ---------------------------------------------------------------------------
__global__ __launch_bounds__(256) void out_gemm_kernel(
    const short* __restrict__ attn16, const short* __restrict__ vT,
    float* __restrict__ out)
{
    __shared__ __attribute__((aligned(16))) short As[128 * BK];
    __shared__ __attribute__((aligned(16))) short Bs[128 * BK];

    const int tid = threadIdx.x;
    const int b  = blockIdx.y;
    const int n0 = blockIdx.x * 128;   // g dim
    const int wave = tid >> 6, lane = tid & 63;
    const int wm = (wave >> 1) * 64, wn = (wave & 1) * 64;
    const int quad = lane >> 4, r = lane & 15;

    const int srow = wave * 32 + (lane >> 2);
    const int scol = (lane & 3) * 8;
    const short* gA = attn16 + (size_t)b * Tn * Tn + srow * Tn + scol;       // t rows, stride 128
    const short* gB = vT + (size_t)(n0 + srow) * MT + b * Tn + scol;         // g rows, stride 2048
    short* lA = &As[srow * BK + scol];
    short* lB = &Bs[srow * BK + scol];

    f32x4 acc[4][4] = {};

    #pragma unroll 1
    for (int k0 = 0; k0 < Tn; k0 += BK) {
        __syncthreads();
        __builtin_amdgcn_global_load_lds(
            (const __attribute__((address_space(1))) void*)(gA + k0),
            (__attribute__((address_space(3))) void*)lA, 16, 0, 0);
        __builtin_amdgcn_global_load_lds(
            (const __attribute__((address_space(1))) void*)(gA + k0 + 16 * Tn),
            (__attribute__((address_space(3))) void*)(lA + 16 * BK), 16, 0, 0);
        __builtin_amdgcn_global_load_lds(
            (const __attribute__((address_space(1))) void*)(gB + k0),
            (__attribute__((address_space(3))) void*)lB, 16, 0, 0);
        __builtin_amdgcn_global_load_lds(
            (const __attribute__((address_space(1))) void*)(gB + k0 + (size_t)16 * MT),
            (__attribute__((address_space(3))) void*)(lB + 16 * BK), 16, 0, 0);
        __syncthreads();

        short8 af[4], bf[4];
        #pragma unroll
        for (int i = 0; i < 4; ++i)
            af[i] = *(const short8*)&As[(wm + i * 16 + r) * BK + quad * 8];
        #pragma unroll
        for (int j = 0; j < 4; ++j)
            bf[j] = *(const short8*)&Bs[(wn + j * 16 + r) * BK + quad * 8];

        #pragma unroll
        for (int i = 0; i < 4; ++i)
            #pragma unroll
            for (int j = 0; j < 4; ++j)
                acc[i][j] = __builtin_amdgcn_mfma_f32_16x16x32_bf16(
                    af[i], bf[j], acc[i][j], 0, 0, 0);
    }

    // C/D: row(m=t)=quad*4+reg, col(n=g)=r group. fp32 out [b][t][g].
    #pragma unroll
    for (int j = 0; j < 4; ++j) {
        const int col = n0 + wn + j * 16 + r;
        #pragma unroll
        for (int i = 0; i < 4; ++i) {
            #pragma unroll
            for (int reg = 0; reg < 4; ++reg) {
                const int rowt = wm + i * 16 + quad * 4 + reg;
                out[((size_t)(b * Tn + rowt)) * Gn + col] = acc[i][j][reg];
            }
        }
    }
}

// ---------------------------------------------------------------------------
extern "C" void kernel_launch(void* const* d_in, const int* in_sizes, int n_in,
                              void* d_out, int out_size, void* d_ws, size_t ws_size,
                              hipStream_t stream)
{
    const float* x1 = (const float*)d_in[0];
    const float* x2 = (const float*)d_in[1];
    const float* w1 = (const float*)d_in[2];
    const float* b1 = (const float*)d_in[3];
    const float* w2 = (const float*)d_in[4];
    const float* b2 = (const float*)d_in[5];
    const float* w3 = (const float*)d_in[6];
    const float* b3 = (const float*)d_in[7];
    float* out = (float*)d_out;

    // Workspace layout: q,k fp32; attn16, vT, x1b, w3b bf16; vTf fp32 x2 (split-K).
    float* q      = (float*)d_ws;
    float* k      = q + MT * Fn;
    short* attn16 = (short*)(k + MT * Fn);
    short* vT     = attn16 + (size_t)Bn * Tn * Tn;
    short* x1b    = vT + (size_t)Gn * MT;
    short* w3b    = x1b + (size_t)MT * Dn;
    float* vTf    = (float*)(w3b + (size_t)Gn * Dn);

    const size_t need_split =
        (size_t)MT * Fn * 4 * 2 +               // q,k
        (size_t)Bn * Tn * Tn * 2 +              // attn16
        (size_t)Gn * MT * 2 +                   // vT
        (size_t)MT * Dn * 2 +                   // x1b
        (size_t)Gn * Dn * 2 +                   // w3b
        (size_t)KSPLIT * Gn * MT * 4;           // vTf partials (64 MB)

    cvt2_kernel<<<4096, 256, 0, stream>>>(x1, w3, x1b, w3b);
    qk_gemm_kernel<<<256, 256, 0, stream>>>(x1b, x2, w1, w2, b1, b2, q, k);
    attn_kernel<<<Bn, 128, 0, stream>>>(q, k, attn16);

    if (ws_size >= need_split) {
        gemm_v_split_kernel<<<dim3(MT / 128, Gn / 128, KSPLIT), 256, 0, stream>>>(
            w3b, x1b, vTf);
        vt_cvt_kernel<<<2048, 256, 0, stream>>>(vTf, b3, vT);
    } else {
        gemm_v_kernel<<<dim3(MT / 128, Gn / 128), 256, 0, stream>>>(w3b, x1b, b3, vT);
    }

    out_gemm_kernel<<<dim3(Gn / 128, Bn), 256, 0, stream>>>(attn16, vT, out);
}

// Round 4
// 548.862 us; speedup vs baseline: 1.1041x; 1.0364x over previous
//
#include <hip/hip_runtime.h>
#include <cstdint>
#include <cstddef>

// Problem constants
#define Bn 16
#define Tn 128
#define Dn 8192    // C*H*W
#define Fn 16      // NUM_FEAT
#define Gn 4096    // NUM_FEAT*H*W
#define MT (Bn*Tn) // 2048 rows

typedef __attribute__((ext_vector_type(8))) short short8;
typedef __attribute__((ext_vector_type(4))) float f32x4;

__device__ inline short f2bf(float f) {
    union { float f; uint32_t u; } c; c.f = f;
    uint32_t u = c.u;
    uint32_t r = (u + 0x7FFFu + ((u >> 16) & 1u)) >> 16;
    return (short)(r & 0xFFFFu);
}

__device__ inline short8 cvt8(float4 a, float4 b) {
    short8 v;
    v[0] = f2bf(a.x); v[1] = f2bf(a.y); v[2] = f2bf(a.z); v[3] = f2bf(a.w);
    v[4] = f2bf(b.x); v[5] = f2bf(b.y); v[6] = f2bf(b.z); v[7] = f2bf(b.w);
    return v;
}

// ---------------------------------------------------------------------------
// Fused fp32->bf16 convert for x1 and w3 (one launch, grid-stride).
// ---------------------------------------------------------------------------
#define N8_X1 (MT * Dn / 8)   // 2,097,152
#define N8_W3 ((size_t)Gn * Dn / 8)   // 4,194,304

__global__ __launch_bounds__(256) void cvt2_kernel(
    const float* __restrict__ x1, const float* __restrict__ w3,
    short* __restrict__ x1b, short* __restrict__ w3b)
{
    const size_t total = N8_X1 + N8_W3;
    size_t i = (size_t)blockIdx.x * 256 + threadIdx.x;
    const size_t stride = (size_t)gridDim.x * 256;
    for (; i < total; i += stride) {
        if (i < N8_X1) {
            const float4* s = ((const float4*)x1) + i * 2;
            ((short8*)x1b)[i] = cvt8(s[0], s[1]);
        } else {
            const size_t j = i - N8_X1;
            const float4* s = ((const float4*)w3) + j * 2;
            ((short8*)w3b)[j] = cvt8(s[0], s[1]);
        }
    }
}

// ---------------------------------------------------------------------------
// qk skinny GEMM: q = x1b @ w1^T + b1 (bf16 A), k = x2 @ w2^T + b2 (inline cvt).
// Grid 256 blocks x 256 threads. Block = (16-row m-tile, q-or-k).
// ---------------------------------------------------------------------------
__global__ __launch_bounds__(256) void qk_gemm_kernel(
    const short* __restrict__ x1b, const float* __restrict__ x2,
    const float* __restrict__ w1, const float* __restrict__ w2,
    const float* __restrict__ b1, const float* __restrict__ b2,
    float* __restrict__ q, float* __restrict__ k)
{
    __shared__ float red[4][16][16];
    const int tid = threadIdx.x;
    const int tile = blockIdx.x >> 1;
    const int isK  = blockIdx.x & 1;
    const int m0 = tile * 16;
    const int wave = tid >> 6, lane = tid & 63;
    const int quad = lane >> 4, r = lane & 15;
    const int kbase = wave * (Dn / 4);   // 2048

    f32x4 acc = {};

    if (!isK) {
        const short* ap = x1b + (size_t)(m0 + r) * Dn + kbase + quad * 8;
        const float* bp = w1 + (size_t)r * Dn + kbase + quad * 8;
        #pragma unroll 4
        for (int it = 0; it < 64; ++it) {
            short8 af = *(const short8*)(ap + it * 32);
            const float4* b4 = (const float4*)(bp + it * 32);
            short8 bf = cvt8(b4[0], b4[1]);
            acc = __builtin_amdgcn_mfma_f32_16x16x32_bf16(af, bf, acc, 0, 0, 0);
        }
    } else {
        const float* apf = x2 + (size_t)(m0 + r) * Dn + kbase + quad * 8;
        const float* bp  = w2 + (size_t)r * Dn + kbase + quad * 8;
        #pragma unroll 4
        for (int it = 0; it < 64; ++it) {
            const float4* a4 = (const float4*)(apf + it * 32);
            short8 af = cvt8(a4[0], a4[1]);
            const float4* b4 = (const float4*)(bp + it * 32);
            short8 bf = cvt8(b4[0], b4[1]);
            acc = __builtin_amdgcn_mfma_f32_16x16x32_bf16(af, bf, acc, 0, 0, 0);
        }
    }

    // C/D: col(n=f)=lane&15, row(m)=quad*4+reg
    #pragma unroll
    for (int reg = 0; reg < 4; ++reg)
        red[wave][quad * 4 + reg][r] = acc[reg];
    __syncthreads();

    const int m = tid >> 4, f = tid & 15;
    float s = red[0][m][f] + red[1][m][f] + red[2][m][f] + red[3][m][f];
    s += (isK ? b2 : b1)[f];
    (isK ? k : q)[(m0 + m) * Fn + f] = s;
}

// ---------------------------------------------------------------------------
// attn: scores = q @ k^T per batch; softmax over t (axis=1 = over rows, i.e.
// per column s). Wave-per-column: grid (Bn, Tn/4) x 256 threads; wave w owns
// column s = blockIdx.y*4 + w; lane owns t=lane and t=lane+64. Butterfly
// shfl reduce for max/sum (exact, not online). Output bf16 [b][t][s].
// ---------------------------------------------------------------------------
__global__ __launch_bounds__(256) void attn_kernel(
    const float* __restrict__ q, const float* __restrict__ k,
    short* __restrict__ attn16)
{
    __shared__ float qs[Tn * 17];
    const int b = blockIdx.x;
    const int tid = threadIdx.x;
    const int wave = tid >> 6, lane = tid & 63;
    const int s = blockIdx.y * 4 + wave;

    for (int i = tid; i < Tn * Fn; i += 256)
        qs[(i >> 4) * 17 + (i & 15)] = q[b * Tn * Fn + i];
    __syncthreads();

    float kr[16];
    #pragma unroll
    for (int f = 0; f < 16; ++f) kr[f] = k[((size_t)b * Tn + s) * Fn + f];

    const int t0 = lane, t1 = lane + 64;
    float sc0 = 0.f, sc1 = 0.f;
    #pragma unroll
    for (int f = 0; f < 16; ++f) {
        sc0 += qs[t0 * 17 + f] * kr[f];
        sc1 += qs[t1 * 17 + f] * kr[f];
    }
    float m = fmaxf(sc0, sc1);
    #pragma unroll
    for (int off = 32; off > 0; off >>= 1)
        m = fmaxf(m, __shfl_xor(m, off, 64));
    const float e0 = __expf(sc0 - m), e1 = __expf(sc1 - m);
    float ssum = e0 + e1;
    #pragma unroll
    for (int off = 32; off > 0; off >>= 1)
        ssum += __shfl_xor(ssum, off, 64);
    const float inv = 1.f / ssum;

    short* ap = attn16 + (size_t)b * Tn * Tn;
    ap[t0 * Tn + s] = f2bf(e0 * inv);
    ap[t1 * Tn + s] = f2bf(e1 * inv);
}

// ---------------------------------------------------------------------------
// Big GEMM, split-K (runtime 2 or 4), DETERMINISTIC: each K-slice z writes its
// own fp32 partial buffer (plain stores — no atomics, no memset, no host API).
// KSPLIT=4: grid (16,32,4)=2048 blocks -> 8 blocks/CU (LDS 128KB<=160,
// VGPR 64 -> 8 waves/SIMD): occupancy cap 50%->100%.
// m97 structure, BK=32, 128x128 tile per block.
// ---------------------------------------------------------------------------
#define BK 32

__global__ __launch_bounds__(256) void gemm_v_split_kernel(
    const short* __restrict__ A, const short* __restrict__ Bw,
    float* __restrict__ vTf, const int kspan)
{
    __shared__ __attribute__((aligned(16))) short As[128 * BK];
    __shared__ __attribute__((aligned(16))) short Bs[128 * BK];

    const int tid = threadIdx.x;
    const int m0 = blockIdx.y * 128;        // g dim (4096)
    const int n0 = blockIdx.x * 128;        // bt dim (2048)
    const int z  = blockIdx.z;              // K slice
    const int kbase = z * kspan;
    float* outp = vTf + (size_t)z * Gn * MT;
    const int wave = tid >> 6, lane = tid & 63;
    const int wm = (wave >> 1) * 64, wn = (wave & 1) * 64;
    const int quad = lane >> 4, r = lane & 15;

    const int srow = wave * 32 + (lane >> 2);
    const int scol = (lane & 3) * 8;
    const short* gA = A  + (size_t)(m0 + srow) * Dn + kbase + scol;
    const short* gB = Bw + (size_t)(n0 + srow) * Dn + kbase + scol;
    short* lA = &As[srow * BK + scol];
    short* lB = &Bs[srow * BK + scol];

    f32x4 acc[4][4] = {};

    #pragma unroll 1
    for (int k0 = 0; k0 < kspan; k0 += BK) {
        __syncthreads();
        __builtin_amdgcn_global_load_lds(
            (const __attribute__((address_space(1))) void*)(gA + k0),
            (__attribute__((address_space(3))) void*)lA, 16, 0, 0);
        __builtin_amdgcn_global_load_lds(
            (const __attribute__((address_space(1))) void*)(gA + k0 + (size_t)16 * Dn),
            (__attribute__((address_space(3))) void*)(lA + 16 * BK), 16, 0, 0);
        __builtin_amdgcn_global_load_lds(
            (const __attribute__((address_space(1))) void*)(gB + k0),
            (__attribute__((address_space(3))) void*)lB, 16, 0, 0);
        __builtin_amdgcn_global_load_lds(
            (const __attribute__((address_space(1))) void*)(gB + k0 + (size_t)16 * Dn),
            (__attribute__((address_space(3))) void*)(lB + 16 * BK), 16, 0, 0);
        __syncthreads();

        short8 af[4], bf[4];
        #pragma unroll
        for (int i = 0; i < 4; ++i)
            af[i] = *(const short8*)&As[(wm + i * 16 + r) * BK + quad * 8];
        #pragma unroll
        for (int j = 0; j < 4; ++j)
            bf[j] = *(const short8*)&Bs[(wn + j * 16 + r) * BK + quad * 8];

        #pragma unroll
        for (int i = 0; i < 4; ++i)
            #pragma unroll
            for (int j = 0; j < 4; ++j)
                acc[i][j] = __builtin_amdgcn_mfma_f32_16x16x32_bf16(
                    af[i], bf[j], acc[i][j], 0, 0, 0);
    }

    // C/D: col(n=bt)=lane&15 group, row(m=g)=quad*4+reg. Plain fp32 stores.
    #pragma unroll
    for (int i = 0; i < 4; ++i) {
        #pragma unroll
        for (int reg = 0; reg < 4; ++reg) {
            const int rowg = m0 + wm + i * 16 + quad * 4 + reg;
            #pragma unroll
            for (int j = 0; j < 4; ++j) {
                const int col = n0 + wn + j * 16 + r;
                outp[(size_t)rowg * MT + col] = acc[i][j][reg];
            }
        }
    }
}

// Sum the nparts K-slice partials + bias, fp32->bf16. row g = i>>8.
__global__ __launch_bounds__(256) void vt_cvt_kernel(
    const float* __restrict__ vTf, const float* __restrict__ bias,
    short* __restrict__ vT, const int nparts)
{
    const size_t N8 = (size_t)Gn * MT / 8;   // 1,048,576
    size_t i = (size_t)blockIdx.x * 256 + threadIdx.x;
    const size_t stride = (size_t)gridDim.x * 256;
    for (; i < N8; i += stride) {
        const float bv = bias[i >> 8];
        float4 a = {bv, bv, bv, bv}, b = {bv, bv, bv, bv};
        for (int p = 0; p < nparts; ++p) {
            const float4* pp = (const float4*)(vTf + (size_t)p * Gn * MT);
            float4 a1 = pp[i * 2], b1 = pp[i * 2 + 1];
            a.x += a1.x; a.y += a1.y; a.z += a1.z; a.w += a1.w;
            b.x += b1.x; b.y += b1.y; b.z += b1.z; b.w += b1.w;
        }
        ((short8*)vT)[i] = cvt8(a, b);
    }
}

// ---------------------------------------------------------------------------
// Fallback (ws too small for split-K): original single-pass big GEMM.
// ---------------------------------------------------------------------------
__global__ __launch_bounds__(256) void gemm_v_kernel(
    const short* __restrict__ A, const short* __restrict__ Bw,
    const float* __restrict__ bias, short* __restrict__ vT)
{
    __shared__ __attribute__((aligned(16))) short As[128 * BK];
    __shared__ __attribute__((aligned(16))) short Bs[128 * BK];

    const int tid = threadIdx.x;
    const int m0 = blockIdx.y * 128;   // g dim (4096)
    const int n0 = blockIdx.x * 128;   // bt dim (2048)
    const int wave = tid >> 6, lane = tid & 63;
    const int wm = (wave >> 1) * 64, wn = (wave & 1) * 64;
    const int quad = lane >> 4, r = lane & 15;

    const int srow = wave * 32 + (lane >> 2);
    const int scol = (lane & 3) * 8;
    const short* gA = A  + (size_t)(m0 + srow) * Dn + scol;
    const short* gB = Bw + (size_t)(n0 + srow) * Dn + scol;
    short* lA = &As[srow * BK + scol];
    short* lB = &Bs[srow * BK + scol];

    f32x4 acc[4][4] = {};

    #pragma unroll 1
    for (int k0 = 0; k0 < Dn; k0 += BK) {
        __syncthreads();
        __builtin_amdgcn_global_load_lds(
            (const __attribute__((address_space(1))) void*)(gA + k0),
            (__attribute__((address_space(3))) void*)lA, 16, 0, 0);
        __builtin_amdgcn_global_load_lds(
            (const __attribute__((address_space(1))) void*)(gA + k0 + (size_t)16 * Dn),
            (__attribute__((address_space(3))) void*)(lA + 16 * BK), 16, 0, 0);
        __builtin_amdgcn_global_load_lds(
            (const __attribute__((address_space(1))) void*)(gB + k0),
            (__attribute__((address_space(3))) void*)lB, 16, 0, 0);
        __builtin_amdgcn_global_load_lds(
            (const __attribute__((address_space(1))) void*)(gB + k0 + (size_t)16 * Dn),
            (__attribute__((address_space(3))) void*)(lB + 16 * BK), 16, 0, 0);
        __syncthreads();

        short8 af[4], bf[4];
        #pragma unroll
        for (int i = 0; i < 4; ++i)
            af[i] = *(const short8*)&As[(wm + i * 16 + r) * BK + quad * 8];
        #pragma unroll
        for (int j = 0; j < 4; ++j)
            bf[j] = *(const short8*)&Bs[(wn + j * 16 + r) * BK + quad * 8];

        #pragma unroll
        for (int i = 0; i < 4; ++i)
            #pragma unroll
            for (int j = 0; j < 4; ++j)
                acc[i][j] = __builtin_amdgcn_mfma_f32_16x16x32_bf16(
                    af[i], bf[j], acc[i][j], 0, 0, 0);
    }

    #pragma unroll
    for (int i = 0; i < 4; ++i) {
        #pragma unroll
        for (int reg = 0; reg < 4; ++reg) {
            const int rowg = m0 + wm + i * 16 + quad * 4 + reg;
            const float bv = bias[rowg];
            #pragma unroll
            for (int j = 0; j < 4; ++j) {
                const int col = n0 + wn + j * 16 + r;
                vT[(size_t)rowg * MT + col] = f2bf(acc[i][j][reg] + bv);
            }
        }
    }
}

// ---------------------------------------------------------------------------
// out GEMM per batch: out[t][g] = sum_s attn[t][s] * vT[g][s].
// 128(t) x 64(g) tile per block -> grid (Gn/64, Bn) = 1024 blocks (4/CU).
// Waves 2x2: wm=(wave>>1)*64, wn=(wave&1)*32; acc[4][2].
// ---------------------------------------------------------------------------
__global__ __launch_bounds__(256) void out_gemm_kernel(
    const short* __restrict__ attn16, const short* __restrict__ vT,
    float* __restrict__ out)
{
    __shared__ __attribute__((aligned(16))) short As[128 * BK];  // 8 KB
    __shared__ __attribute__((aligned(16))) short Bs[64 * BK];   // 4 KB

    const int tid = threadIdx.x;
    const int b  = blockIdx.y;
    const int n0 = blockIdx.x * 64;    // g dim
    const int wave = tid >> 6, lane = tid & 63;
    const int wm = (wave >> 1) * 64, wn = (wave & 1) * 32;
    const int quad = lane >> 4, r = lane & 15;

    const int srowA = wave * 32 + (lane >> 2);   // 0..127 over 2 instrs
    const int srowB = wave * 16 + (lane >> 2);   // 0..63, 1 instr
    const int scol = (lane & 3) * 8;
    const short* gA = attn16 + (size_t)b * Tn * Tn + srowA * Tn + scol;   // t rows
    const short* gB = vT + (size_t)(n0 + srowB) * MT + b * Tn + scol;     // g rows
    short* lA = &As[srowA * BK + scol];
    short* lB = &Bs[srowB * BK + scol];

    f32x4 acc[4][2] = {};

    #pragma unroll 1
    for (int k0 = 0; k0 < Tn; k0 += BK) {
        __syncthreads();
        __builtin_amdgcn_global_load_lds(
            (const __attribute__((address_space(1))) void*)(gA + k0),
            (__attribute__((address_space(3))) void*)lA, 16, 0, 0);
        __builtin_amdgcn_global_load_lds(
            (const __attribute__((address_space(1))) void*)(gA + k0 + 16 * Tn),
            (__attribute__((address_space(3))) void*)(lA + 16 * BK), 16, 0, 0);
        __builtin_amdgcn_global_load_lds(
            (const __attribute__((address_space(1))) void*)(gB + k0),
            (__attribute__((address_space(3))) void*)lB, 16, 0, 0);
        __syncthreads();

        short8 af[4], bf[2];
        #pragma unroll
        for (int i = 0; i < 4; ++i)
            af[i] = *(const short8*)&As[(wm + i * 16 + r) * BK + quad * 8];
        #pragma unroll
        for (int j = 0; j < 2; ++j)
            bf[j] = *(const short8*)&Bs[(wn + j * 16 + r) * BK + quad * 8];

        #pragma unroll
        for (int i = 0; i < 4; ++i)
            #pragma unroll
            for (int j = 0; j < 2; ++j)
                acc[i][j] = __builtin_amdgcn_mfma_f32_16x16x32_bf16(
                    af[i], bf[j], acc[i][j], 0, 0, 0);
    }

    // C/D: row(m=t)=quad*4+reg, col(n=g)=r group. fp32 out [b][t][g].
    #pragma unroll
    for (int j = 0; j < 2; ++j) {
        const int col = n0 + wn + j * 16 + r;
        #pragma unroll
        for (int i = 0; i < 4; ++i) {
            #pragma unroll
            for (int reg = 0; reg < 4; ++reg) {
                const int rowt = wm + i * 16 + quad * 4 + reg;
                out[((size_t)(b * Tn + rowt)) * Gn + col] = acc[i][j][reg];
            }
        }
    }
}

// ---------------------------------------------------------------------------
extern "C" void kernel_launch(void* const* d_in, const int* in_sizes, int n_in,
                              void* d_out, int out_size, void* d_ws, size_t ws_size,
                              hipStream_t stream)
{
    const float* x1 = (const float*)d_in[0];
    const float* x2 = (const float*)d_in[1];
    const float* w1 = (const float*)d_in[2];
    const float* b1 = (const float*)d_in[3];
    const float* w2 = (const float*)d_in[4];
    const float* b2 = (const float*)d_in[5];
    const float* w3 = (const float*)d_in[6];
    const float* b3 = (const float*)d_in[7];
    float* out = (float*)d_out;

    // Workspace layout: q,k fp32; attn16, vT, x1b, w3b bf16; vTf fp32 xK (split-K).
    float* q      = (float*)d_ws;
    float* k      = q + MT * Fn;
    short* attn16 = (short*)(k + MT * Fn);
    short* vT     = attn16 + (size_t)Bn * Tn * Tn;
    short* x1b    = vT + (size_t)Gn * MT;
    short* w3b    = x1b + (size_t)MT * Dn;
    float* vTf    = (float*)(w3b + (size_t)Gn * Dn);

    const size_t base_need =
        (size_t)MT * Fn * 4 * 2 +               // q,k
        (size_t)Bn * Tn * Tn * 2 +              // attn16
        (size_t)Gn * MT * 2 +                   // vT
        (size_t)MT * Dn * 2 +                   // x1b
        (size_t)Gn * Dn * 2;                    // w3b
    const size_t psize = (size_t)Gn * MT * 4;   // 32 MB per partial

    int ksplit = 0;
    if (ws_size >= base_need + 4 * psize)      ksplit = 4;
    else if (ws_size >= base_need + 2 * psize) ksplit = 2;

    cvt2_kernel<<<4096, 256, 0, stream>>>(x1, w3, x1b, w3b);
    qk_gemm_kernel<<<256, 256, 0, stream>>>(x1b, x2, w1, w2, b1, b2, q, k);
    attn_kernel<<<dim3(Bn, Tn / 4), 256, 0, stream>>>(q, k, attn16);

    if (ksplit) {
        gemm_v_split_kernel<<<dim3(MT / 128, Gn / 128, ksplit), 256, 0, stream>>>(
            w3b, x1b, vTf, Dn / ksplit);
        vt_cvt_kernel<<<2048, 256, 0, stream>>>(vTf, b3, vT, ksplit);
    } else {
        gemm_v_kernel<<<dim3(MT / 128, Gn / 128), 256, 0, stream>>>(w3b, x1b, b3, vT);
    }

    out_gemm_kernel<<<dim3(Gn / 64, Bn), 256, 0, stream>>>(attn16, vT, out);
}